// Round 3
// baseline (491.953 us; speedup 1.0000x reference)
//
#include <hip/hip_runtime.h>
#include <hip/hip_bf16.h>
#include <stdint.h>

// Fused Kronecker-factorized linear via bf16-split MFMA (3-product fp32 emulation):
//   out[b, 128*gp + g] = sum_{r,f} x[b, 128*r + f] * w0[f][g] * w1[r][gp]
//   i.e. per batch: Out = W1^T * X * W0, all 128x128.
//
// Kernel 1 (prep): split w0/w1 into bf16 hi/lo, laid out in MFMA-fragment order
//   in d_ws so the main kernel loads one coalesced 16B/lane chunk per fragment.
// Kernel 2 (main): 1 block per batch element, 4 waves (2x2 wave grid, each wave
//   owns a 64x64 output quadrant = 4x4 tiles of 16x16).
//   Phase 1: T = X*W0   (A=X from LDS hi/lo, B=W0 frags from d_ws/L2)
//   Phase 2: O = W1^T*T (A=W1^T frags from d_ws/L2, B=T from LDS hi/lo)
//   LDS 64 KB total (X hi/lo reused as T hi/lo) -> 2 blocks/CU for overlap.
//
// Fragment convention (both kernels share it): for mfma_f32_16x16x32_bf16,
//   lane l supplies operand elements j=0..7 at k = (l>>4)*8 + j;
//   A row / B col = l&15. Result is invariant to the true hardware k-slot
//   permutation as long as A and B use the SAME convention (it cancels).
//   C/D layout (HW-verified): col = l&15, row = (l>>4)*4 + reg.
//
// LDS swizzle: rows of 128 bf16 = 256 B = 16 chunks of 16 B.
//   chunk' = chunk ^ (row&15)  -> fragment reads (16 lanes, 16 rows, same
//   chunk) hit 16 distinct chunks -> conflict-free.

typedef unsigned short u16;
typedef __attribute__((ext_vector_type(8))) short short8;
typedef __attribute__((ext_vector_type(4))) float float4v;

__device__ __forceinline__ uint32_t pk_bf16(float a, float b) {
    // packs bf16(a) in low 16, bf16(b) in high 16 (RNE)
    __hip_bfloat162 h = __float22bfloat162_rn(make_float2(a, b));
    uint32_t u;
    __builtin_memcpy(&u, &h, 4);
    return u;
}

// ---------------- Kernel 1: weight fragment prep ----------------
// d_ws layout (u16 units): [0]=W0hi, [16384]=W0lo, [32768]=W1hi, [49152]=W1lo.
// Fragment linear index r = ((ktile*8 + tile)*64 + lane)*8 + j.
// W0 (phase-1 B): value = w0[k][n],  n = tile*16 + (l&15)
// W1 (phase-2 A): value = w1[k][m],  m = tile*16 + (l&15)   (A = W1^T)
// both with k = ktile*32 + (l>>4)*8 + j.
__global__ void prep_weights(const float* __restrict__ w0,
                             const float* __restrict__ w1,
                             u16* __restrict__ wsp) {
    const int tid = blockIdx.x * 256 + threadIdx.x;  // 0..32767
    const int m  = tid >> 14;                        // 0: w0, 1: w1
    const int r  = tid & 16383;
    const int fi = r >> 9;        // 0..31
    const int l  = (r >> 3) & 63;
    const int j  = r & 7;
    const int ktile = fi >> 3, tile = fi & 7;
    const int k = ktile * 32 + (l >> 4) * 8 + j;
    const int c = tile * 16 + (l & 15);
    const float v = (m ? w1 : w0)[k * 128 + c];

    const uint32_t hu = pk_bf16(v, 0.0f);
    const u16 hb = (u16)(hu & 0xFFFF);
    const float hf = __uint_as_float(hu << 16);
    const u16 lb = (u16)(pk_bf16(v - hf, 0.0f) & 0xFFFF);

    u16* base = wsp + m * 32768;
    base[r] = hb;
    base[16384 + r] = lb;
}

// ---------------- Kernel 2: fused sandwich ----------------
__global__ __launch_bounds__(256, 2) void faclin_mfma(
    const float* __restrict__ x,     // (B, 16384)
    const u16* __restrict__ wsp,     // prepped weight frags
    float* __restrict__ out)         // (B, 16384)
{
    __shared__ alignas(16) u16 Hs[16384];  // X hi, then T hi (32 KB)
    __shared__ alignas(16) u16 Ls[16384];  // X lo, then T lo (32 KB)

    const int b = blockIdx.x;
    const int t = threadIdx.x;
    const float* __restrict__ xb = x + (size_t)b * 16384;
    float* __restrict__ ob = out + (size_t)b * 16384;

    // ---- Stage X -> bf16 hi/lo in LDS (swizzled row-major) ----
    {
        const float4* __restrict__ src = (const float4*)xb;
        const int row_s  = t >> 5;
        const int cf     = (t & 31) * 4;  // float col base
        const int chunk  = cf >> 3;       // 16B chunk in row
        const int within = cf & 7;        // 0 or 4 (u16 elems)
        #pragma unroll
        for (int i = 0; i < 16; ++i) {
            const int row = i * 8 + row_s;
            const float4 v = src[i * 256 + t];
            const uint32_t h01 = pk_bf16(v.x, v.y);
            const uint32_t h23 = pk_bf16(v.z, v.w);
            const float hx = __uint_as_float(h01 << 16);
            const float hy = __uint_as_float(h01 & 0xFFFF0000u);
            const float hz = __uint_as_float(h23 << 16);
            const float hw = __uint_as_float(h23 & 0xFFFF0000u);
            const uint32_t l01 = pk_bf16(v.x - hx, v.y - hy);
            const uint32_t l23 = pk_bf16(v.z - hz, v.w - hw);
            const int addr = row * 128 + ((chunk ^ (row & 15)) * 8) + within;
            *(uint64_t*)&Hs[addr] = (uint64_t)h01 | ((uint64_t)h23 << 32);
            *(uint64_t*)&Ls[addr] = (uint64_t)l01 | ((uint64_t)l23 << 32);
        }
    }
    __syncthreads();

    const int l   = t & 63;
    const int w   = t >> 6;
    const int wm  = (w >> 1) * 64;  // wave's output row quadrant
    const int wn  = (w & 1) * 64;   // wave's output col quadrant
    const int l15 = l & 15, lg = l >> 4;

    const u16* __restrict__ W0h = wsp;
    const u16* __restrict__ W0l = wsp + 16384;
    const u16* __restrict__ W1h = wsp + 32768;
    const u16* __restrict__ W1l = wsp + 49152;

    // ---- Phase 1: T[r][g] = sum_f X[r][f] * w0[f][g] ----
    float4v acc[4][4];
    #pragma unroll
    for (int i = 0; i < 4; ++i)
        #pragma unroll
        for (int j = 0; j < 4; ++j) acc[i][j] = {0.f, 0.f, 0.f, 0.f};

    #pragma unroll
    for (int kt = 0; kt < 4; ++kt) {
        short8 ah[4], al[4], bh[4], bl[4];
        #pragma unroll
        for (int mt = 0; mt < 4; ++mt) {
            const int row = wm + mt * 16 + l15;
            const int chunk = kt * 4 + lg;
            const int addr = row * 128 + ((chunk ^ (row & 15)) * 8);
            ah[mt] = *(const short8*)&Hs[addr];
            al[mt] = *(const short8*)&Ls[addr];
        }
        #pragma unroll
        for (int nt = 0; nt < 4; ++nt) {
            const int fi = kt * 8 + (wn >> 4) + nt;
            const int off = (fi * 64 + l) * 8;
            bh[nt] = *(const short8*)&W0h[off];
            bl[nt] = *(const short8*)&W0l[off];
        }
        #pragma unroll
        for (int mt = 0; mt < 4; ++mt)
            #pragma unroll
            for (int nt = 0; nt < 4; ++nt) {
                acc[mt][nt] = __builtin_amdgcn_mfma_f32_16x16x32_bf16(al[mt], bh[nt], acc[mt][nt], 0, 0, 0);
                acc[mt][nt] = __builtin_amdgcn_mfma_f32_16x16x32_bf16(ah[mt], bl[nt], acc[mt][nt], 0, 0, 0);
                acc[mt][nt] = __builtin_amdgcn_mfma_f32_16x16x32_bf16(ah[mt], bh[nt], acc[mt][nt], 0, 0, 0);
            }
    }
    __syncthreads();  // all X reads complete before T overwrites the buffers

    // ---- T -> bf16 hi/lo, column-major (Ts[g][r]) swizzled, reusing Hs/Ls ----
    // acc tile (mt,nt) reg q: r = wm + mt*16 + lg*4 + q, g = wn + nt*16 + l15.
    // 4 regs = 4 consecutive r -> one 8B write per tile per array.
    #pragma unroll
    for (int mt = 0; mt < 4; ++mt)
        #pragma unroll
        for (int nt = 0; nt < 4; ++nt) {
            const int r0 = wm + mt * 16 + lg * 4;
            const int g  = wn + nt * 16 + l15;
            const float4v a = acc[mt][nt];
            const uint32_t h01 = pk_bf16(a[0], a[1]);
            const uint32_t h23 = pk_bf16(a[2], a[3]);
            const float f0 = __uint_as_float(h01 << 16);
            const float f1 = __uint_as_float(h01 & 0xFFFF0000u);
            const float f2 = __uint_as_float(h23 << 16);
            const float f3 = __uint_as_float(h23 & 0xFFFF0000u);
            const uint32_t l01 = pk_bf16(a[0] - f0, a[1] - f1);
            const uint32_t l23 = pk_bf16(a[2] - f2, a[3] - f3);
            const int addr = g * 128 + (((r0 >> 3) ^ (g & 15)) * 8) + (r0 & 7);
            *(uint64_t*)&Hs[addr] = (uint64_t)h01 | ((uint64_t)h23 << 32);
            *(uint64_t*)&Ls[addr] = (uint64_t)l01 | ((uint64_t)l23 << 32);
        }
    __syncthreads();

    // ---- Phase 2: O[gp][g] = sum_r w1[r][gp] * T[r][g] ----
    float4v acc2[4][4];
    #pragma unroll
    for (int i = 0; i < 4; ++i)
        #pragma unroll
        for (int j = 0; j < 4; ++j) acc2[i][j] = {0.f, 0.f, 0.f, 0.f};

    #pragma unroll
    for (int kt = 0; kt < 4; ++kt) {
        short8 ah[4], al[4], bh[4], bl[4];
        #pragma unroll
        for (int mt = 0; mt < 4; ++mt) {
            const int fi = kt * 8 + (wm >> 4) + mt;
            const int off = (fi * 64 + l) * 8;
            ah[mt] = *(const short8*)&W1h[off];
            al[mt] = *(const short8*)&W1l[off];
        }
        #pragma unroll
        for (int nt = 0; nt < 4; ++nt) {
            const int n = wn + nt * 16 + l15;
            const int chunk = kt * 4 + lg;
            const int addr = n * 128 + ((chunk ^ (n & 15)) * 8);
            bh[nt] = *(const short8*)&Hs[addr];
            bl[nt] = *(const short8*)&Ls[addr];
        }
        #pragma unroll
        for (int mt = 0; mt < 4; ++mt)
            #pragma unroll
            for (int nt = 0; nt < 4; ++nt) {
                acc2[mt][nt] = __builtin_amdgcn_mfma_f32_16x16x32_bf16(al[mt], bh[nt], acc2[mt][nt], 0, 0, 0);
                acc2[mt][nt] = __builtin_amdgcn_mfma_f32_16x16x32_bf16(ah[mt], bl[nt], acc2[mt][nt], 0, 0, 0);
                acc2[mt][nt] = __builtin_amdgcn_mfma_f32_16x16x32_bf16(ah[mt], bh[nt], acc2[mt][nt], 0, 0, 0);
            }
    }

    // ---- Store O (fp32). C/D: row = (l>>4)*4 + q, col = l&15 per 16x16 tile.
    #pragma unroll
    for (int mt = 0; mt < 4; ++mt)
        #pragma unroll
        for (int nt = 0; nt < 4; ++nt)
            #pragma unroll
            for (int q = 0; q < 4; ++q) {
                const int orow = wm + mt * 16 + lg * 4 + q;
                const int ocol = wn + nt * 16 + l15;
                ob[orow * 128 + ocol] = acc2[mt][nt][q];
            }
}

extern "C" void kernel_launch(void* const* d_in, const int* in_sizes, int n_in,
                              void* d_out, int out_size, void* d_ws, size_t ws_size,
                              hipStream_t stream) {
    const float* x  = (const float*)d_in[0];
    const float* w0 = (const float*)d_in[1];
    const float* w1 = (const float*)d_in[2];
    float* out = (float*)d_out;
    u16* wsp = (u16*)d_ws;  // needs 128 KB

    const int B = in_sizes[0] >> 14;  // 4096

    prep_weights<<<128, 256, 0, stream>>>(w0, w1, wsp);
    faclin_mfma<<<B, 256, 0, stream>>>(x, (const u16*)wsp, out);
}